// Round 2
// baseline (430.045 us; speedup 1.0000x reference)
//
#include <hip/hip_runtime.h>
#include <hip/hip_bf16.h>
#include <stdint.h>

// Problem constants (fixed by reference: B=8, Q=4096, E=1024, M=256)
#define TOK 32768
#define EMB 1024
#define MSL 256

typedef __attribute__((ext_vector_type(8))) short short8;   // 8 bf16 = 4 VGPRs (MFMA A/B frag)
typedef __attribute__((ext_vector_type(4))) float f32x4;    // MFMA C/D frag

__device__ __forceinline__ ushort f2bf(float f) {
    union { float f; uint32_t u; } c; c.f = f;
    uint32_t u = c.u;
    return (ushort)((u + 0x7fffu + ((u >> 16) & 1u)) >> 16);  // RNE
}

// truncation split: f = hi + lo with |f - hi - lo| <= 2^-16 |f|
__device__ __forceinline__ void split2(float f, ushort& h, ushort& l) {
    union { float f; uint32_t u; } c; c.f = f;
    h = (ushort)(c.u >> 16);
    union { uint32_t u; float f; } hv; hv.u = c.u & 0xffff0000u;
    union { float f; uint32_t u; } lc; lc.f = f - hv.f;
    l = (ushort)(lc.u >> 16);
}

__device__ __forceinline__ void async_copy16(const void* gsrc, void* ldst) {
    // wave-uniform LDS base + lane*16 semantics (guide §5)
    __builtin_amdgcn_global_load_lds(
        (const __attribute__((address_space(1))) uint32_t*)gsrc,
        (__attribute__((address_space(3))) uint32_t*)ldst,
        16, 0, 0);
}

// ---------------- fp32 -> (hi, lo) bf16 split, vectorized ----------------
__global__ __launch_bounds__(256) void split_f32(const float* __restrict__ in,
                                                 ushort* __restrict__ hi,
                                                 ushort* __restrict__ lo) {
    int i = blockIdx.x * 256 + threadIdx.x;          // grid = n/4/256
    float4 v = ((const float4*)in)[i];
    ushort4 h4, l4;
    split2(v.x, h4.x, l4.x); split2(v.y, h4.y, l4.y);
    split2(v.z, h4.z, l4.z); split2(v.w, h4.w, l4.w);
    ((ushort4*)hi)[i] = h4;
    ((ushort4*)lo)[i] = l4;
}

// ---------------- Wq [F][E] -> WqT hi/lo [E][F], LDS-tiled 64x64 ----------------
__global__ __launch_bounds__(256) void transpose_split(const float* __restrict__ in,
                                                       ushort* __restrict__ outh,
                                                       ushort* __restrict__ outl) {
    __shared__ float ld[64 * 65];
    const int t = threadIdx.x;
    const int eBase = blockIdx.x * 64;
    const int fBase = blockIdx.y * 64;
    #pragma unroll
    for (int r = 0; r < 16; ++r) {
        int row = r * 4 + (t >> 6);      // f within tile
        int col = t & 63;                // e within tile
        ld[row * 65 + col] = in[(size_t)(fBase + row) * EMB + eBase + col];
    }
    __syncthreads();
    #pragma unroll
    for (int r = 0; r < 16; ++r) {
        int row = r * 4 + (t >> 6);      // e within tile
        int col = t & 63;                // f within tile
        float v = ld[col * 65 + row];    // = in[fBase+col][eBase+row]
        ushort h, l; split2(v, h, l);
        size_t o = (size_t)(eBase + row) * EMB + fBase + col;
        outh[o] = h; outl[o] = l;
    }
}

// ---------------- c[m] = dot(bq, mb[m]) , one wave per m ----------------
__global__ __launch_bounds__(256) void dot_c(const float* __restrict__ bq,
                                             const float* __restrict__ mb,
                                             float* __restrict__ c) {
    int m = blockIdx.x * 4 + (threadIdx.x >> 6);
    int lane = threadIdx.x & 63;
    const float4* mrow = (const float4*)(mb + (size_t)m * EMB);
    const float4* brow = (const float4*)bq;
    float s = 0.f;
    #pragma unroll
    for (int k = 0; k < 4; ++k) {
        float4 a = mrow[lane + k * 64];
        float4 b = brow[lane + k * 64];
        s += a.x * b.x + a.y * b.y + a.z * b.z + a.w * b.w;
    }
    #pragma unroll
    for (int off = 32; off; off >>= 1) s += __shfl_xor(s, off, 64);
    if (lane == 0) c[m] = s;
}

// ---------------- softmax over M=256, one wave per row ----------------
__global__ __launch_bounds__(256) void softmax_rows(const float* __restrict__ scores,
                                                    ushort* __restrict__ w) {
    int row = blockIdx.x * 4 + (threadIdx.x >> 6);
    int lane = threadIdx.x & 63;
    const float4 v = ((const float4*)(scores + (size_t)row * MSL))[lane];
    float mx = fmaxf(fmaxf(v.x, v.y), fmaxf(v.z, v.w));
    #pragma unroll
    for (int off = 32; off; off >>= 1) mx = fmaxf(mx, __shfl_xor(mx, off, 64));
    float e0 = __expf(v.x - mx), e1 = __expf(v.y - mx);
    float e2 = __expf(v.z - mx), e3 = __expf(v.w - mx);
    float s = e0 + e1 + e2 + e3;
    #pragma unroll
    for (int off = 32; off; off >>= 1) s += __shfl_xor(s, off, 64);
    float inv = 1.0f / s;
    ushort4 o;
    o.x = f2bf(e0 * inv); o.y = f2bf(e1 * inv); o.z = f2bf(e2 * inv); o.w = f2bf(e3 * inv);
    ((ushort4*)(w + (size_t)row * MSL))[lane] = o;
}

// ---- split-precision GEMM: C[n,c] = sum_k A_f32[n,k] * (Bh+Bl)[c,k] (+bias[c]) ----
// A is fp32, split to (hi,lo) bf16 during LDS staging (truncation split).
// C = Ah*Bh + Ah*Bl + Al*Bh  (fp32 MFMA accumulate) -> ~fp32 precision.
// Block tile 128x128, BK=64, 256 threads = 4 waves (2x2), wave tile 64x64.
template<bool ADD_BIAS, bool OUT_BF16>
__global__ __launch_bounds__(256) void gemm_s(
    const float* __restrict__ A, const ushort* __restrict__ Bh,
    const ushort* __restrict__ Bl, const float* __restrict__ bias,
    void* __restrict__ Cout, int K, int ldc)
{
    __shared__ ushort sAh[128 * 64];   // 16 KiB each, 64 KiB total
    __shared__ ushort sAl[128 * 64];
    __shared__ ushort sBh[128 * 64];
    __shared__ ushort sBl[128 * 64];

    const int t = threadIdx.x;
    const int lane = t & 63;
    const int wave = t >> 6;
    const int wr = wave >> 1;
    const int wc = wave & 1;
    const int rowBase = blockIdx.y * 128;
    const int colBase = blockIdx.x * 128;

    const float*  Ab  = A  + (size_t)rowBase * K;
    const ushort* Bhb = Bh + (size_t)colBase * K;
    const ushort* Blb = Bl + (size_t)colBase * K;

    f32x4 acc[4][4] = {};

    const int kIters = K >> 6;
    for (int kt = 0; kt < kIters; ++kt) {
        const int k0 = kt << 6;
        __syncthreads();
        // B tiles: async global->LDS (bf16, pre-split)
        #pragma unroll
        for (int r = 0; r < 4; ++r) {
            int i = r * 256 + t;
            int row = i >> 3;
            int col = (i & 7) << 3;
            async_copy16(Bhb + (size_t)row * K + k0 + col, &sBh[(size_t)(r * 256 + wave * 64) * 8]);
            async_copy16(Blb + (size_t)row * K + k0 + col, &sBl[(size_t)(r * 256 + wave * 64) * 8]);
        }
        // A tile: fp32 load -> in-register truncation split -> LDS (hi & lo)
        #pragma unroll
        for (int r = 0; r < 4; ++r) {
            int i = r * 256 + t;
            int row = i >> 3;
            int col = (i & 7) << 3;
            const float* src = Ab + (size_t)row * K + k0 + col;
            float4 f0 = *(const float4*)src;
            float4 f1 = *(const float4*)(src + 4);
            short8 hv, lv; ushort h, l;
            split2(f0.x, h, l); hv[0] = (short)h; lv[0] = (short)l;
            split2(f0.y, h, l); hv[1] = (short)h; lv[1] = (short)l;
            split2(f0.z, h, l); hv[2] = (short)h; lv[2] = (short)l;
            split2(f0.w, h, l); hv[3] = (short)h; lv[3] = (short)l;
            split2(f1.x, h, l); hv[4] = (short)h; lv[4] = (short)l;
            split2(f1.y, h, l); hv[5] = (short)h; lv[5] = (short)l;
            split2(f1.z, h, l); hv[6] = (short)h; lv[6] = (short)l;
            split2(f1.w, h, l); hv[7] = (short)h; lv[7] = (short)l;
            *(short8*)&sAh[(size_t)i * 8] = hv;
            *(short8*)&sAl[(size_t)i * 8] = lv;
        }
        __syncthreads();

        #pragma unroll
        for (int ks = 0; ks < 2; ++ks) {
            const int kloc = ks * 32 + (lane >> 4) * 8;
            short8 ah[4], al[4], bh[4], bl[4];
            #pragma unroll
            for (int i2 = 0; i2 < 4; ++i2) {
                int row = wr * 64 + i2 * 16 + (lane & 15);
                ah[i2] = *(const short8*)&sAh[row * 64 + kloc];
                al[i2] = *(const short8*)&sAl[row * 64 + kloc];
            }
            #pragma unroll
            for (int j = 0; j < 4; ++j) {
                int row = wc * 64 + j * 16 + (lane & 15);
                bh[j] = *(const short8*)&sBh[row * 64 + kloc];
                bl[j] = *(const short8*)&sBl[row * 64 + kloc];
            }
            #pragma unroll
            for (int i2 = 0; i2 < 4; ++i2)
                #pragma unroll
                for (int j = 0; j < 4; ++j) {
                    acc[i2][j] = __builtin_amdgcn_mfma_f32_16x16x32_bf16(ah[i2], bh[j], acc[i2][j], 0, 0, 0);
                    acc[i2][j] = __builtin_amdgcn_mfma_f32_16x16x32_bf16(ah[i2], bl[j], acc[i2][j], 0, 0, 0);
                    acc[i2][j] = __builtin_amdgcn_mfma_f32_16x16x32_bf16(al[i2], bh[j], acc[i2][j], 0, 0, 0);
                }
        }
    }

    // epilogue: C/D layout col=lane&15, row=(lane>>4)*4+reg  [verified m89/m91]
    #pragma unroll
    for (int i2 = 0; i2 < 4; ++i2) {
        #pragma unroll
        for (int j = 0; j < 4; ++j) {
            const int col = colBase + wc * 64 + j * 16 + (lane & 15);
            float bcol = ADD_BIAS ? bias[col] : 0.0f;
            #pragma unroll
            for (int r = 0; r < 4; ++r) {
                const int row = rowBase + wr * 64 + i2 * 16 + ((lane >> 4) << 2) + r;
                float v = acc[i2][j][r] + bcol;
                if (OUT_BF16)
                    ((ushort*)Cout)[(size_t)row * ldc + col] = f2bf(v);
                else
                    ((float*)Cout)[(size_t)row * ldc + col] = v;
            }
        }
    }
}

// ---------------- plain bf16 GEMM: C[n,f] = sum_k A[n,k]*B[f,k] (+bias)(+resid) ----
template<bool ADD_BIAS, bool ADD_RESID, bool OUT_BF16>
__global__ __launch_bounds__(256) void gemm_bt(
    const ushort* __restrict__ A, const ushort* __restrict__ Bm,
    const float* __restrict__ bias, const float* __restrict__ resid,
    void* __restrict__ Cout, int K, int ldc)
{
    __shared__ ushort sA[128 * 64];   // 16 KiB
    __shared__ ushort sB[128 * 64];   // 16 KiB

    const int t = threadIdx.x;
    const int lane = t & 63;
    const int wave = t >> 6;
    const int wr = wave >> 1;
    const int wc = wave & 1;
    const int rowBase = blockIdx.y * 128;
    const int colBase = blockIdx.x * 128;

    const ushort* Ab = A + (size_t)rowBase * K;
    const ushort* Bb = Bm + (size_t)colBase * K;

    f32x4 acc[4][4] = {};

    const int kIters = K >> 6;
    for (int kt = 0; kt < kIters; ++kt) {
        const int k0 = kt << 6;
        __syncthreads();
        #pragma unroll
        for (int r = 0; r < 4; ++r) {
            int i = r * 256 + t;
            int row = i >> 3;
            int col = (i & 7) << 3;
            async_copy16(Ab + (size_t)row * K + k0 + col, &sA[(size_t)(r * 256 + wave * 64) * 8]);
        }
        #pragma unroll
        for (int r = 0; r < 4; ++r) {
            int i = r * 256 + t;
            int row = i >> 3;
            int col = (i & 7) << 3;
            async_copy16(Bb + (size_t)row * K + k0 + col, &sB[(size_t)(r * 256 + wave * 64) * 8]);
        }
        __syncthreads();

        #pragma unroll
        for (int ks = 0; ks < 2; ++ks) {
            const int kloc = ks * 32 + (lane >> 4) * 8;
            short8 a[4], b[4];
            #pragma unroll
            for (int i2 = 0; i2 < 4; ++i2) {
                int row = wr * 64 + i2 * 16 + (lane & 15);
                a[i2] = *(const short8*)&sA[row * 64 + kloc];
            }
            #pragma unroll
            for (int j = 0; j < 4; ++j) {
                int row = wc * 64 + j * 16 + (lane & 15);
                b[j] = *(const short8*)&sB[row * 64 + kloc];
            }
            #pragma unroll
            for (int i2 = 0; i2 < 4; ++i2)
                #pragma unroll
                for (int j = 0; j < 4; ++j)
                    acc[i2][j] = __builtin_amdgcn_mfma_f32_16x16x32_bf16(
                        a[i2], b[j], acc[i2][j], 0, 0, 0);
        }
    }

    #pragma unroll
    for (int i2 = 0; i2 < 4; ++i2) {
        #pragma unroll
        for (int j = 0; j < 4; ++j) {
            const int col = colBase + wc * 64 + j * 16 + (lane & 15);
            float bcol = ADD_BIAS ? bias[col] : 0.0f;
            #pragma unroll
            for (int r = 0; r < 4; ++r) {
                const int row = rowBase + wr * 64 + i2 * 16 + ((lane >> 4) << 2) + r;
                float v = acc[i2][j][r] + bcol;
                if (ADD_RESID) v += resid[(size_t)row * ldc + col];
                if (OUT_BF16)
                    ((ushort*)Cout)[(size_t)row * ldc + col] = f2bf(v);
                else
                    ((float*)Cout)[(size_t)row * ldc + col] = v;
            }
        }
    }
}

extern "C" void kernel_launch(void* const* d_in, const int* in_sizes, int n_in,
                              void* d_out, int out_size, void* d_ws, size_t ws_size,
                              hipStream_t stream) {
    const float* x  = (const float*)d_in[0];   // [TOK, EMB]
    const float* mb = (const float*)d_in[1];   // [MSL, EMB]
    const float* Wq = (const float*)d_in[2];   // [EMB, EMB]
    const float* bq = (const float*)d_in[3];   // [EMB]
    const float* Wo = (const float*)d_in[4];   // [EMB, EMB]
    const float* bo = (const float*)d_in[5];   // [EMB]
    float* out = (float*)d_out;                // [TOK, EMB]

    // workspace layout (~56 MB)
    char* ws = (char*)d_ws;
    size_t o = 0;
    float*  sc   = (float*)(ws + o);  o += (size_t)TOK * MSL * 4;   // scores fp32 (32 MB)
    ushort* wgt  = (ushort*)(ws + o); o += (size_t)TOK * MSL * 2;   // softmax weights bf16 (16 MB)
    ushort* mbh  = (ushort*)(ws + o); o += (size_t)MSL * EMB * 2;   // mb hi
    ushort* mbl  = (ushort*)(ws + o); o += (size_t)MSL * EMB * 2;   // mb lo
    ushort* wqth = (ushort*)(ws + o); o += (size_t)EMB * EMB * 2;   // Wq^T hi
    ushort* wqtl = (ushort*)(ws + o); o += (size_t)EMB * EMB * 2;   // Wq^T lo
    float*  P    = (float*)(ws + o);  o += (size_t)MSL * EMB * 4;   // P fp32
    ushort* Ph   = (ushort*)(ws + o); o += (size_t)MSL * EMB * 2;
    ushort* Pl   = (ushort*)(ws + o); o += (size_t)MSL * EMB * 2;
    ushort* RTb  = (ushort*)(ws + o); o += (size_t)EMB * MSL * 2;   // RT bf16 [EMB, MSL]
    float*  cvec = (float*)(ws + o);  o += (size_t)MSL * 4;

    // --- small precomputes (all fold the fixed memory bank into the projections) ---
    split_f32<<<(MSL * EMB / 4) / 256, 256, 0, stream>>>(mb, mbh, mbl);
    transpose_split<<<dim3(16, 16), 256, 0, stream>>>(Wq, wqth, wqtl);
    dot_c<<<MSL / 4, 256, 0, stream>>>(bq, mb, cvec);

    // P[m,e] = sum_f mb[m,f] * WqT[e,f]   (fp32-accurate via split GEMM)
    gemm_s<false, false><<<dim3(EMB / 128, MSL / 128), 256, 0, stream>>>(
        mb, wqth, wqtl, nullptr, P, EMB, EMB);
    split_f32<<<(MSL * EMB / 4) / 256, 256, 0, stream>>>(P, Ph, Pl);

    // RT[f,m] = sum_e Wo[f,e] * mb[m,e]  -> bf16 [EMB, MSL]
    gemm_s<false, true><<<dim3(MSL / 128, EMB / 128), 256, 0, stream>>>(
        Wo, mbh, mbl, nullptr, RTb, EMB, MSL);

    // scores[n,m] = sum_e x[n,e] * P[m,e] + c[m]   (~fp32-accurate)
    gemm_s<true, false><<<dim3(MSL / 128, TOK / 128), 256, 0, stream>>>(
        x, Ph, Pl, cvec, sc, EMB, MSL);

    // softmax rows -> bf16 weights
    softmax_rows<<<TOK / 4, 256, 0, stream>>>(sc, wgt);

    // out[n,f] = sum_m w[n,m] * RT[f,m] + bo[f] + x[n,f]
    gemm_bt<true, true, false><<<dim3(EMB / 128, TOK / 128), 256, 0, stream>>>(
        wgt, RTb, bo, x, out, MSL, EMB);
}

// Round 3
// 374.049 us; speedup vs baseline: 1.1497x; 1.1497x over previous
//
#include <hip/hip_runtime.h>
#include <hip/hip_bf16.h>
#include <stdint.h>

// Problem constants (fixed by reference: B=8, Q=4096, E=1024, M=256)
#define TOK 32768
#define EMB 1024
#define MSL 256

typedef __attribute__((ext_vector_type(8))) short short8;   // 8 bf16 = 4 VGPRs (MFMA A/B frag)
typedef __attribute__((ext_vector_type(4))) float f32x4;    // MFMA C/D frag

__device__ __forceinline__ ushort f2bf(float f) {
    union { float f; uint32_t u; } c; c.f = f;
    uint32_t u = c.u;
    return (ushort)((u + 0x7fffu + ((u >> 16) & 1u)) >> 16);  // RNE
}

// truncation split: f = hi + lo with |f - hi - lo| <= 2^-16 |f|
__device__ __forceinline__ void split2(float f, ushort& h, ushort& l) {
    union { float f; uint32_t u; } c; c.f = f;
    h = (ushort)(c.u >> 16);
    union { uint32_t u; float f; } hv; hv.u = c.u & 0xffff0000u;
    union { float f; uint32_t u; } lc; lc.f = f - hv.f;
    l = (ushort)(lc.u >> 16);
}

__device__ __forceinline__ void async_copy16(const void* gsrc, void* ldst) {
    // wave-uniform LDS base + lane*16 semantics (guide §5)
    __builtin_amdgcn_global_load_lds(
        (const __attribute__((address_space(1))) uint32_t*)gsrc,
        (__attribute__((address_space(3))) uint32_t*)ldst,
        16, 0, 0);
}

// ---------------- zero fp32 buffer (vectorized) ----------------
__global__ __launch_bounds__(256) void zero_f32(float* __restrict__ p) {
    int i = blockIdx.x * 256 + threadIdx.x;
    ((float4*)p)[i] = float4{0.f, 0.f, 0.f, 0.f};
}

// ---------------- fp32 -> bf16 cast ----------------
__global__ __launch_bounds__(256) void cast_f32_bf16(const float* __restrict__ in,
                                                     ushort* __restrict__ out) {
    int i = blockIdx.x * 256 + threadIdx.x;
    float4 v = ((const float4*)in)[i];
    ushort4 o;
    o.x = f2bf(v.x); o.y = f2bf(v.y); o.z = f2bf(v.z); o.w = f2bf(v.w);
    ((ushort4*)out)[i] = o;
}

// ---------------- fp32 -> (hi, lo) bf16 split, vectorized ----------------
__global__ __launch_bounds__(256) void split_f32(const float* __restrict__ in,
                                                 ushort* __restrict__ hi,
                                                 ushort* __restrict__ lo) {
    int i = blockIdx.x * 256 + threadIdx.x;          // grid = n/4/256
    float4 v = ((const float4*)in)[i];
    ushort4 h4, l4;
    split2(v.x, h4.x, l4.x); split2(v.y, h4.y, l4.y);
    split2(v.z, h4.z, l4.z); split2(v.w, h4.w, l4.w);
    ((ushort4*)hi)[i] = h4;
    ((ushort4*)lo)[i] = l4;
}

// ---------------- Wq [F][E] -> WqT hi/lo [E][F], LDS-tiled 64x64 ----------------
__global__ __launch_bounds__(256) void transpose_split(const float* __restrict__ in,
                                                       ushort* __restrict__ outh,
                                                       ushort* __restrict__ outl) {
    __shared__ float ld[64 * 65];
    const int t = threadIdx.x;
    const int eBase = blockIdx.x * 64;
    const int fBase = blockIdx.y * 64;
    #pragma unroll
    for (int r = 0; r < 16; ++r) {
        int row = r * 4 + (t >> 6);      // f within tile
        int col = t & 63;                // e within tile
        ld[row * 65 + col] = in[(size_t)(fBase + row) * EMB + eBase + col];
    }
    __syncthreads();
    #pragma unroll
    for (int r = 0; r < 16; ++r) {
        int row = r * 4 + (t >> 6);      // e within tile
        int col = t & 63;                // f within tile
        float v = ld[col * 65 + row];    // = in[fBase+col][eBase+row]
        ushort h, l; split2(v, h, l);
        size_t o = (size_t)(eBase + row) * EMB + fBase + col;
        outh[o] = h; outl[o] = l;
    }
}

// ---------------- c[m] = dot(bq, mb[m]) , one wave per m ----------------
__global__ __launch_bounds__(256) void dot_c(const float* __restrict__ bq,
                                             const float* __restrict__ mb,
                                             float* __restrict__ c) {
    int m = blockIdx.x * 4 + (threadIdx.x >> 6);
    int lane = threadIdx.x & 63;
    const float4* mrow = (const float4*)(mb + (size_t)m * EMB);
    const float4* brow = (const float4*)bq;
    float s = 0.f;
    #pragma unroll
    for (int k = 0; k < 4; ++k) {
        float4 a = mrow[lane + k * 64];
        float4 b = brow[lane + k * 64];
        s += a.x * b.x + a.y * b.y + a.z * b.z + a.w * b.w;
    }
    #pragma unroll
    for (int off = 32; off; off >>= 1) s += __shfl_xor(s, off, 64);
    if (lane == 0) c[m] = s;
}

// ---------------- softmax over M=256, one wave per row ----------------
__global__ __launch_bounds__(256) void softmax_rows(const float* __restrict__ scores,
                                                    ushort* __restrict__ w) {
    int row = blockIdx.x * 4 + (threadIdx.x >> 6);
    int lane = threadIdx.x & 63;
    const float4 v = ((const float4*)(scores + (size_t)row * MSL))[lane];
    float mx = fmaxf(fmaxf(v.x, v.y), fmaxf(v.z, v.w));
    #pragma unroll
    for (int off = 32; off; off >>= 1) mx = fmaxf(mx, __shfl_xor(mx, off, 64));
    float e0 = __expf(v.x - mx), e1 = __expf(v.y - mx);
    float e2 = __expf(v.z - mx), e3 = __expf(v.w - mx);
    float s = e0 + e1 + e2 + e3;
    #pragma unroll
    for (int off = 32; off; off >>= 1) s += __shfl_xor(s, off, 64);
    float inv = 1.0f / s;
    ushort4 o;
    o.x = f2bf(e0 * inv); o.y = f2bf(e1 * inv); o.z = f2bf(e2 * inv); o.w = f2bf(e3 * inv);
    ((ushort4*)(w + (size_t)row * MSL))[lane] = o;
}

// XOR swizzle: LDS slot (row, c) holds global 16B-chunk (c ^ (row&7)) of that row.
// Writers keep lane-flat LDS addresses (global source permuted -> same coalescing);
// readers XOR the chunk column by row&7 -> 16-lane phases spread over all 32 banks.

// ---- split-precision GEMM: C[n,c] = sum_k A_f32[n,k] * (Bh+Bl)[c,k] (+bias[c]) ----
// C = Ah*Bh + Ah*Bl + Al*Bh  (fp32 MFMA accumulate) -> ~fp32 precision.
// Block tile 128x128, BK=64, 256 threads = 4 waves (2x2), wave tile 64x64.
// ATOMIC: split-K over gridDim.z, fp32 atomicAdd epilogue (buffer must be pre-zeroed).
template<bool ADD_BIAS, bool OUT_BF16, bool ATOMIC>
__global__ __launch_bounds__(256) void gemm_s(
    const float* __restrict__ A, const ushort* __restrict__ Bh,
    const ushort* __restrict__ Bl, const float* __restrict__ bias,
    void* __restrict__ Cout, int K, int ldc)
{
    __shared__ ushort sAh[128 * 64];   // 16 KiB each, 64 KiB total
    __shared__ ushort sAl[128 * 64];
    __shared__ ushort sBh[128 * 64];
    __shared__ ushort sBl[128 * 64];

    const int t = threadIdx.x;
    const int lane = t & 63;
    const int wave = t >> 6;
    const int wr = wave >> 1;
    const int wc = wave & 1;
    const int rowBase = blockIdx.y * 128;
    const int colBase = blockIdx.x * 128;

    const float*  Ab  = A  + (size_t)rowBase * K;
    const ushort* Bhb = Bh + (size_t)colBase * K;
    const ushort* Blb = Bl + (size_t)colBase * K;

    // staging source-chunk permutation (constant per thread)
    const int cg = ((t & 7) ^ ((t >> 3) & 7)) << 3;   // element offset of swizzled chunk

    f32x4 acc[4][4] = {};

    const int kIters = (K >> 6) / (ATOMIC ? gridDim.z : 1);
    const int ktBase = ATOMIC ? blockIdx.z * kIters : 0;
    for (int kt = ktBase; kt < ktBase + kIters; ++kt) {
        const int k0 = kt << 6;
        __syncthreads();
        // B tiles: async global->LDS (bf16, pre-split), swizzled source
        #pragma unroll
        for (int r = 0; r < 4; ++r) {
            int row = r * 32 + (t >> 3);
            async_copy16(Bhb + (size_t)row * K + k0 + cg, &sBh[(size_t)(r * 256 + wave * 64) * 8]);
            async_copy16(Blb + (size_t)row * K + k0 + cg, &sBl[(size_t)(r * 256 + wave * 64) * 8]);
        }
        // A tile: fp32 load (swizzled source) -> in-register split -> LDS hi/lo
        #pragma unroll
        for (int r = 0; r < 4; ++r) {
            int i = r * 256 + t;
            int row = r * 32 + (t >> 3);
            const float* src = Ab + (size_t)row * K + k0 + cg;
            float4 f0 = *(const float4*)src;
            float4 f1 = *(const float4*)(src + 4);
            short8 hv, lv; ushort h, l;
            split2(f0.x, h, l); hv[0] = (short)h; lv[0] = (short)l;
            split2(f0.y, h, l); hv[1] = (short)h; lv[1] = (short)l;
            split2(f0.z, h, l); hv[2] = (short)h; lv[2] = (short)l;
            split2(f0.w, h, l); hv[3] = (short)h; lv[3] = (short)l;
            split2(f1.x, h, l); hv[4] = (short)h; lv[4] = (short)l;
            split2(f1.y, h, l); hv[5] = (short)h; lv[5] = (short)l;
            split2(f1.z, h, l); hv[6] = (short)h; lv[6] = (short)l;
            split2(f1.w, h, l); hv[7] = (short)h; lv[7] = (short)l;
            *(short8*)&sAh[(size_t)i * 8] = hv;
            *(short8*)&sAl[(size_t)i * 8] = lv;
        }
        __syncthreads();

        #pragma unroll
        for (int ks = 0; ks < 2; ++ks) {
            const int kc = ks * 4 + (lane >> 4);      // 16B chunk column
            short8 ah[4], al[4], bh[4], bl[4];
            #pragma unroll
            for (int i2 = 0; i2 < 4; ++i2) {
                int row = wr * 64 + i2 * 16 + (lane & 15);
                int off = row * 64 + ((kc ^ (row & 7)) << 3);
                ah[i2] = *(const short8*)&sAh[off];
                al[i2] = *(const short8*)&sAl[off];
            }
            #pragma unroll
            for (int j = 0; j < 4; ++j) {
                int row = wc * 64 + j * 16 + (lane & 15);
                int off = row * 64 + ((kc ^ (row & 7)) << 3);
                bh[j] = *(const short8*)&sBh[off];
                bl[j] = *(const short8*)&sBl[off];
            }
            #pragma unroll
            for (int i2 = 0; i2 < 4; ++i2)
                #pragma unroll
                for (int j = 0; j < 4; ++j) {
                    acc[i2][j] = __builtin_amdgcn_mfma_f32_16x16x32_bf16(ah[i2], bh[j], acc[i2][j], 0, 0, 0);
                    acc[i2][j] = __builtin_amdgcn_mfma_f32_16x16x32_bf16(ah[i2], bl[j], acc[i2][j], 0, 0, 0);
                    acc[i2][j] = __builtin_amdgcn_mfma_f32_16x16x32_bf16(al[i2], bh[j], acc[i2][j], 0, 0, 0);
                }
        }
    }

    // epilogue: C/D layout col=lane&15, row=(lane>>4)*4+reg  [verified m89/m91]
    #pragma unroll
    for (int i2 = 0; i2 < 4; ++i2) {
        #pragma unroll
        for (int j = 0; j < 4; ++j) {
            const int col = colBase + wc * 64 + j * 16 + (lane & 15);
            float bcol = ADD_BIAS ? bias[col] : 0.0f;
            #pragma unroll
            for (int r = 0; r < 4; ++r) {
                const int row = rowBase + wr * 64 + i2 * 16 + ((lane >> 4) << 2) + r;
                float v = acc[i2][j][r] + bcol;
                if (ATOMIC)
                    atomicAdd(&((float*)Cout)[(size_t)row * ldc + col], v);
                else if (OUT_BF16)
                    ((ushort*)Cout)[(size_t)row * ldc + col] = f2bf(v);
                else
                    ((float*)Cout)[(size_t)row * ldc + col] = v;
            }
        }
    }
}

// ---------------- plain bf16 GEMM: C[n,f] = sum_k A[n,k]*B[f,k] (+bias)(+resid) ----
template<bool ADD_BIAS, bool ADD_RESID, bool OUT_BF16>
__global__ __launch_bounds__(256) void gemm_bt(
    const ushort* __restrict__ A, const ushort* __restrict__ Bm,
    const float* __restrict__ bias, const float* __restrict__ resid,
    void* __restrict__ Cout, int K, int ldc)
{
    __shared__ ushort sA[128 * 64];   // 16 KiB
    __shared__ ushort sB[128 * 64];   // 16 KiB

    const int t = threadIdx.x;
    const int lane = t & 63;
    const int wave = t >> 6;
    const int wr = wave >> 1;
    const int wc = wave & 1;
    const int rowBase = blockIdx.y * 128;
    const int colBase = blockIdx.x * 128;

    const ushort* Ab = A + (size_t)rowBase * K;
    const ushort* Bb = Bm + (size_t)colBase * K;

    const int cg = ((t & 7) ^ ((t >> 3) & 7)) << 3;

    f32x4 acc[4][4] = {};

    const int kIters = K >> 6;
    for (int kt = 0; kt < kIters; ++kt) {
        const int k0 = kt << 6;
        __syncthreads();
        #pragma unroll
        for (int r = 0; r < 4; ++r) {
            int row = r * 32 + (t >> 3);
            async_copy16(Ab + (size_t)row * K + k0 + cg, &sA[(size_t)(r * 256 + wave * 64) * 8]);
            async_copy16(Bb + (size_t)row * K + k0 + cg, &sB[(size_t)(r * 256 + wave * 64) * 8]);
        }
        __syncthreads();

        #pragma unroll
        for (int ks = 0; ks < 2; ++ks) {
            const int kc = ks * 4 + (lane >> 4);
            short8 a[4], b[4];
            #pragma unroll
            for (int i2 = 0; i2 < 4; ++i2) {
                int row = wr * 64 + i2 * 16 + (lane & 15);
                a[i2] = *(const short8*)&sA[row * 64 + ((kc ^ (row & 7)) << 3)];
            }
            #pragma unroll
            for (int j = 0; j < 4; ++j) {
                int row = wc * 64 + j * 16 + (lane & 15);
                b[j] = *(const short8*)&sB[row * 64 + ((kc ^ (row & 7)) << 3)];
            }
            #pragma unroll
            for (int i2 = 0; i2 < 4; ++i2)
                #pragma unroll
                for (int j = 0; j < 4; ++j)
                    acc[i2][j] = __builtin_amdgcn_mfma_f32_16x16x32_bf16(
                        a[i2], b[j], acc[i2][j], 0, 0, 0);
        }
    }

    #pragma unroll
    for (int i2 = 0; i2 < 4; ++i2) {
        #pragma unroll
        for (int j = 0; j < 4; ++j) {
            const int col = colBase + wc * 64 + j * 16 + (lane & 15);
            float bcol = ADD_BIAS ? bias[col] : 0.0f;
            #pragma unroll
            for (int r = 0; r < 4; ++r) {
                const int row = rowBase + wr * 64 + i2 * 16 + ((lane >> 4) << 2) + r;
                float v = acc[i2][j][r] + bcol;
                if (ADD_RESID) v += resid[(size_t)row * ldc + col];
                if (OUT_BF16)
                    ((ushort*)Cout)[(size_t)row * ldc + col] = f2bf(v);
                else
                    ((float*)Cout)[(size_t)row * ldc + col] = v;
            }
        }
    }
}

extern "C" void kernel_launch(void* const* d_in, const int* in_sizes, int n_in,
                              void* d_out, int out_size, void* d_ws, size_t ws_size,
                              hipStream_t stream) {
    const float* x  = (const float*)d_in[0];   // [TOK, EMB]
    const float* mb = (const float*)d_in[1];   // [MSL, EMB]
    const float* Wq = (const float*)d_in[2];   // [EMB, EMB]
    const float* bq = (const float*)d_in[3];   // [EMB]
    const float* Wo = (const float*)d_in[4];   // [EMB, EMB]
    const float* bo = (const float*)d_in[5];   // [EMB]
    float* out = (float*)d_out;                // [TOK, EMB]

    // workspace layout (~58 MB). P and RTf adjacent -> single zero pass.
    char* ws = (char*)d_ws;
    size_t o = 0;
    float*  P    = (float*)(ws + o);  o += (size_t)MSL * EMB * 4;   // P fp32 (atomic dst)
    float*  RTf  = (float*)(ws + o);  o += (size_t)EMB * MSL * 4;   // RT fp32 (atomic dst)
    float*  sc   = (float*)(ws + o);  o += (size_t)TOK * MSL * 4;   // scores fp32 (32 MB)
    ushort* wgt  = (ushort*)(ws + o); o += (size_t)TOK * MSL * 2;   // softmax weights bf16
    ushort* mbh  = (ushort*)(ws + o); o += (size_t)MSL * EMB * 2;   // mb hi
    ushort* mbl  = (ushort*)(ws + o); o += (size_t)MSL * EMB * 2;   // mb lo
    ushort* wqth = (ushort*)(ws + o); o += (size_t)EMB * EMB * 2;   // Wq^T hi
    ushort* wqtl = (ushort*)(ws + o); o += (size_t)EMB * EMB * 2;   // Wq^T lo
    ushort* Ph   = (ushort*)(ws + o); o += (size_t)MSL * EMB * 2;
    ushort* Pl   = (ushort*)(ws + o); o += (size_t)MSL * EMB * 2;
    ushort* RTb  = (ushort*)(ws + o); o += (size_t)EMB * MSL * 2;   // RT bf16 [EMB, MSL]
    float*  cvec = (float*)(ws + o);  o += (size_t)MSL * 4;

    // zero atomic destinations (P + RTf contiguous: 2*MSL*EMB floats)
    zero_f32<<<(2 * MSL * EMB / 4) / 256, 256, 0, stream>>>(P);

    // --- small precomputes (fold the fixed memory bank into the projections) ---
    split_f32<<<(MSL * EMB / 4) / 256, 256, 0, stream>>>(mb, mbh, mbl);
    transpose_split<<<dim3(16, 16), 256, 0, stream>>>(Wq, wqth, wqtl);
    dot_c<<<MSL / 4, 256, 0, stream>>>(bq, mb, cvec);

    // P[m,e] = sum_f mb[m,f] * WqT[e,f]  — split-K (16 chunks), atomic fp32
    gemm_s<false, false, true><<<dim3(EMB / 128, MSL / 128, 16), 256, 0, stream>>>(
        mb, wqth, wqtl, nullptr, P, EMB, EMB);
    split_f32<<<(MSL * EMB / 4) / 256, 256, 0, stream>>>(P, Ph, Pl);

    // RT[f,m] = sum_e Wo[f,e] * mb[m,e]  — split-K, atomic fp32, then cast
    gemm_s<false, false, true><<<dim3(MSL / 128, EMB / 128, 16), 256, 0, stream>>>(
        Wo, mbh, mbl, nullptr, RTf, EMB, MSL);
    cast_f32_bf16<<<(EMB * MSL / 4) / 256, 256, 0, stream>>>(RTf, RTb);

    // scores[n,m] = sum_e x[n,e] * P[m,e] + c[m]   (~fp32-accurate)
    gemm_s<true, false, false><<<dim3(MSL / 128, TOK / 128, 1), 256, 0, stream>>>(
        x, Ph, Pl, cvec, sc, EMB, MSL);

    // softmax rows -> bf16 weights
    softmax_rows<<<TOK / 4, 256, 0, stream>>>(sc, wgt);

    // out[n,f] = sum_m w[n,m] * RT[f,m] + bo[f] + x[n,f]
    gemm_bt<true, true, false><<<dim3(EMB / 128, TOK / 128), 256, 0, stream>>>(
        wgt, RTb, bo, x, out, MSL, EMB);
}